// Round 6
// baseline (48.721 us; speedup 1.0000x reference)
//
#include <hip/hip_runtime.h>
#include <hip/hip_bf16.h>
#include <hip/hip_fp16.h>

typedef __attribute__((ext_vector_type(8))) short short8;   // 8 x bf16 (4 VGPRs)
typedef __attribute__((ext_vector_type(4))) float f32x4;    // MFMA accumulator

#define OUT_F  11008
#define IN_F   4096
#define BN     64
#define SPLITS 4
#define KSTEPS 8              // 128-wide K steps per split (4*8*128 = 4096)
#define NB     (OUT_F / BN)   // 172
#define WB     8192           // one RAW W buffer: 64 rows x 128 B
#define NBUF   3
#define NGRP   (OUT_F * IN_F / 128)   // 352256 quant groups

// workspace layout (bytes)
#define WS_RNG  0                        // float2 {xmin, dd} per group: 2818048 B
#define WS_XB   (NGRP * 8)               // bf16 x: 32*4096*2 = 262144 B
#define WS_PART (WS_XB + 32 * IN_F * 2)  // split-K partials: 4*32*11008*4 B

// ---------- helpers ----------
static __device__ __forceinline__ uint pack2_bf16(float a, float b) {
    __hip_bfloat162 h = __float22bfloat162_rn(make_float2(a, b));
    uint u;
    __builtin_memcpy(&u, &h, 4);
    return u;
}

static __device__ __forceinline__ float bf16_to_f(ushort u) {
    return __uint_as_float(((uint)u) << 16);
}

// dequant 8 weights (2 packed ints, low bytes) -> short8 bf16
static __device__ __forceinline__ short8 dq8(int2 p, float xmin, float dd) {
    uint u0 = pack2_bf16(fmaf((float)(p.x & 3), dd, xmin),
                         fmaf((float)((p.x >> 2) & 3), dd, xmin));
    uint u1 = pack2_bf16(fmaf((float)((p.x >> 4) & 3), dd, xmin),
                         fmaf((float)((p.x >> 6) & 3), dd, xmin));
    uint u2 = pack2_bf16(fmaf((float)(p.y & 3), dd, xmin),
                         fmaf((float)((p.y >> 2) & 3), dd, xmin));
    uint u3 = pack2_bf16(fmaf((float)((p.y >> 4) & 3), dd, xmin),
                         fmaf((float)((p.y >> 6) & 3), dd, xmin));
    uint4 q = make_uint4(u0, u1, u2, u3);
    short8 r;
    __builtin_memcpy(&r, &q, 16);
    return r;
}

static __device__ __forceinline__ void gload16(const void* g, void* l) {
    __builtin_amdgcn_global_load_lds((const __attribute__((address_space(1))) void*)g,
                                     (__attribute__((address_space(3))) void*)l,
                                     16, 0, 0);
}

// ---------- kernel 1: x->bf16, detect range dtype, decode all ranges ----------
__global__ __launch_bounds__(256)
void prep_kernel(const float* __restrict__ x,
                 const void* __restrict__ rr,
                 char* __restrict__ ws) {
    const int b = blockIdx.x;
    const int t = threadIdx.x;
    if (b < 128) {
        // x: 32*4096 f32 -> bf16; 4/thread; 128*256*4 = 131072
        const int i = b * 256 + t;
        const float4 v = ((const float4*)x)[i];
        ushort4 o;
        __hip_bfloat16 h0 = __float2bfloat16(v.x);
        __hip_bfloat16 h1 = __float2bfloat16(v.y);
        __hip_bfloat16 h2 = __float2bfloat16(v.z);
        __hip_bfloat16 h3 = __float2bfloat16(v.w);
        __builtin_memcpy(&o.x, &h0, 2);
        __builtin_memcpy(&o.y, &h1, 2);
        __builtin_memcpy(&o.z, &h2, 2);
        __builtin_memcpy(&o.w, &h3, 2);
        ((ushort4*)(ws + WS_XB))[i] = o;
        return;
    }
    // ---- block-local dtype detection (identical logic to passing round 5) ----
    __shared__ int s_viol[3];
    __shared__ int s_max[3];
    __shared__ int s_fmt;
    if (t < 3) { s_viol[t] = 0; s_max[t] = 0; }
    __syncthreads();
    {
        const int g = 1024 + t;   // f32-view reads bytes [8192,10240): in-bounds for all fmts
        const uint   ru = ((const uint*)rr)[g];
        const float2 rf = ((const float2*)rr)[g];
        int viol[3]; float mx[3];
        {   // h0: fp16 pairs
            __half2 h; __builtin_memcpy(&h, &ru, 4);
            const float a = __half2float(h.x), c = __half2float(h.y);
            viol[0] = !(fabsf(a) < 1.f && fabsf(c) < 1.f && a <= c);
            mx[0] = fabsf(c);
        }
        {   // h1: bf16 pairs
            const float a = bf16_to_f((ushort)(ru & 0xffff));
            const float c = bf16_to_f((ushort)(ru >> 16));
            viol[1] = !(fabsf(a) < 1.f && fabsf(c) < 1.f && a <= c);
            mx[1] = fabsf(c);
        }
        {   // h2: f32 pairs
            viol[2] = !(fabsf(rf.x) < 1.f && fabsf(rf.y) < 1.f && rf.x <= rf.y);
            mx[2] = fabsf(rf.y);
        }
#pragma unroll
        for (int h = 0; h < 3; ++h) {
            if (viol[h]) atomicOr(&s_viol[h], 1);
            atomicMax(&s_max[h], __float_as_int(mx[h]));   // mx >= 0: int-monotone
        }
    }
    __syncthreads();
    if (t == 0) {
        const float lo = 0.02f;
        int f = 0;
        if      (!s_viol[2] && __int_as_float(s_max[2]) > lo) f = 2;
        else if (!s_viol[1] && __int_as_float(s_max[1]) > lo) f = 1;
        s_fmt = f;
    }
    __syncthreads();
    const int fmt = s_fmt;

    // ---- decode 1024 groups -> float2{xmin, dd} ----
    const int bi = b - 128;            // 0..343; 344*1024 = 352256 = NGRP exactly
    float2* dst = (float2*)(ws + WS_RNG);
#pragma unroll
    for (int j = 0; j < 4; ++j) {
        const int g = bi * 1024 + j * 256 + t;
        float xmin, xmax;
        if (fmt == 2) {
            const float2 f = ((const float2*)rr)[g];
            xmin = f.x; xmax = f.y;
        } else if (fmt == 1) {
            const uint u = ((const uint*)rr)[g];
            xmin = bf16_to_f((ushort)(u & 0xffff));
            xmax = bf16_to_f((ushort)(u >> 16));
        } else {
            uint u = ((const uint*)rr)[g];
            __half2 h; __builtin_memcpy(&h, &u, 4);
            xmin = __half2float(h.x); xmax = __half2float(h.y);
        }
        dst[g] = make_float2(xmin, (xmax - xmin) * (1.0f / 3.0f));
    }
}

// ---------- kernel 2: GEMM with raw-packed LDS + dequant-on-read ----------
__global__ __launch_bounds__(256, 4)
void gemm_kernel(const int* __restrict__ packed,
                 const char* __restrict__ ws,
                 float* __restrict__ part) {
    const int nb   = blockIdx.x;   // 0..171 (64 output cols)
    const int s    = blockIdx.y;   // 0..3   (K split)
    const int t    = threadIdx.x;
    const int lane = t & 63;
    const int wv   = t >> 6;

    const float2* rng = (const float2*)(ws + WS_RNG);
    const ushort* xb  = (const ushort*)(ws + WS_XB);

    __shared__ __align__(16) char lds[NBUF * WB];   // 3 x raw 64x128B W tiles

    // ---- staging (gload_lds, linear dest; inverse-swizzled global source) ----
    // lane L of wave wv stages rows {wv*8 + (L>>3), +32}, 16 B at logical off
    // ((L&7)*16) ^ ((row&7)<<4); LDS dest = base + wv*1024 (+4096) + L*16 (HW).
    const int sr0 = wv * 8 + (lane >> 3);
    const int sr1 = sr0 + 32;
    const char* gs0 = (const char*)(packed + (size_t)(nb * BN + sr0) * 1024)
                      + (uint)(((lane & 7) * 16) ^ ((sr0 & 7) << 4));
    const char* gs1 = (const char*)(packed + (size_t)(nb * BN + sr1) * 1024)
                      + (uint)(((lane & 7) * 16) ^ ((sr1 & 7) << 4));

    // ---- consumer ----
    const int  nrow   = (wv << 4) | (lane & 15);          // W row this lane feeds
    const int  rngidx = (nb * BN + nrow) * 32;
    const ushort* xa  = xb + (lane & 15) * IN_F + ((lane >> 4) << 3);
    const uint ob  = (uint)((lane >> 4) << 3);            // 8-B k-slice offset
    const uint rsw = (uint)((nrow & 7) << 4);             // read swizzle

    f32x4 acc0 = {0.f, 0.f, 0.f, 0.f};
    f32x4 acc1 = {0.f, 0.f, 0.f, 0.f};
    const int kb0 = s * KSTEPS;

    // ---- prologue: stage step 0 -> buf 0; range pair step 0 ----
    gload16(gs0 + kb0 * 128, lds + wv * 1024);
    gload16(gs1 + kb0 * 128, lds + 4096 + wv * 1024);
    float2 rc = rng[rngidx + kb0];

    for (int step = 0; step < KSTEPS; ++step) {
        const int kb = kb0 + step;

        // (1) A fragments for this step (xb is L1/L2-hot)
        short8 a0[4], a1[4];
        const ushort* xk = xa + (kb << 7);
#pragma unroll
        for (int kc = 0; kc < 4; ++kc) {
            a0[kc] = *(const short8*)(xk + kc * 32);
            a1[kc] = *(const short8*)(xk + 16 * IN_F + kc * 32);
        }

        // (2,3) next range pair + stage next W tile (stays in flight past barrier)
        float2 rn = rc;
        if (step + 1 < KSTEPS) {
            const int kn = kb + 1;
            rn = rng[rngidx + kn];
            char* db = lds + ((step + 1) % NBUF) * WB + wv * 1024;
            gload16(gs0 + kn * 128, db);
            gload16(gs1 + kn * 128, db + 4096);
        }

        // (4,5) counted-vmcnt handoff: per iter issues 8 A + 1 rng + 2 stage = 11;
        // vmcnt(8) drains (at least) the PREVIOUS stage pair, never this one.
        asm volatile("s_waitcnt vmcnt(8)" ::: "memory");
        __builtin_amdgcn_s_barrier();
        __builtin_amdgcn_sched_barrier(0);

        // (6,7) dequant-on-read + MFMA
        const char* wt = lds + (step % NBUF) * WB + nrow * 128;
#pragma unroll
        for (int kc = 0; kc < 4; ++kc) {
            const uint off = ((uint)(kc * 32) | ob) ^ rsw;
            int2 pq = *(const int2*)(wt + off);            // ds_read_b64
            short8 bf = dq8(pq, rc.x, rc.y);
            acc0 = __builtin_amdgcn_mfma_f32_16x16x32_bf16(a0[kc], bf, acc0, 0, 0, 0);
            acc1 = __builtin_amdgcn_mfma_f32_16x16x32_bf16(a1[kc], bf, acc1, 0, 0, 0);
        }
        rc = rn;
    }

    // ---- epilogue: split-K partial stores ----
    // C/D layout col=lane&15, row=(lane>>4)*4+reg (m89-verified)
    float* pout = part + (size_t)s * (32 * OUT_F);
    const int col = nb * BN + nrow;
    const int r0  = (lane >> 4) << 2;
#pragma unroll
    for (int v = 0; v < 4; ++v) {
        pout[(r0 + v) * OUT_F + col]      = acc0[v];
        pout[(16 + r0 + v) * OUT_F + col] = acc1[v];
    }
}

// ---------- kernel 3: out = bias + sum of split-K partials ----------
__global__ __launch_bounds__(256)
void reduce_kernel(const float* __restrict__ part,
                   const float* __restrict__ bias,
                   float* __restrict__ out) {
    const int i = blockIdx.x * 256 + threadIdx.x;   // 0..88063 float4 units
    const int n4 = i % 2752;                        // 11008/4
    const float4* p4 = (const float4*)part;
    float4 a = ((const float4*)bias)[n4];
#pragma unroll
    for (int ss = 0; ss < SPLITS; ++ss) {
        const float4 v = p4[ss * 88064 + i];
        a.x += v.x; a.y += v.y; a.z += v.z; a.w += v.w;
    }
    ((float4*)out)[i] = a;
}

extern "C" void kernel_launch(void* const* d_in, const int* in_sizes, int n_in,
                              void* d_out, int out_size, void* d_ws, size_t ws_size,
                              hipStream_t stream) {
    const float* x      = (const float*)d_in[0];
    const int*   packed = (const int*)d_in[1];
    const void*  rr     = (const void*)d_in[2];
    const float* bias   = (const float*)d_in[3];
    float*       out    = (float*)d_out;
    char*        ws     = (char*)d_ws;
    float*       part   = (float*)(ws + WS_PART);

    prep_kernel<<<472, 256, 0, stream>>>(x, rr, ws);
    gemm_kernel<<<dim3(NB, SPLITS), 256, 0, stream>>>(packed, ws, part);
    reduce_kernel<<<344, 256, 0, stream>>>(part, bias, out);
}